// Round 12
// baseline (1048.508 us; speedup 1.0000x reference)
//
#include <hip/hip_runtime.h>
#include <hip/hip_bf16.h>
#include <stdint.h>

// Problem constants (from reference)
#define V_SZ 32000
#define D_SZ 1024          // = K
#define M_SZ 8192          // B*S = 4*2048

typedef __attribute__((ext_vector_type(8))) short bf16x8;
typedef __attribute__((ext_vector_type(4))) float f32x4;
typedef __attribute__((ext_vector_type(16))) float f32x16;

static __device__ __forceinline__ unsigned short f32_to_bf16_rne(float f) {
    union { float f; uint32_t u; } v; v.f = f;
    uint32_t u = v.u;
    uint32_t lsb = (u >> 16) & 1;
    u += 0x7fffu + lsb;
    return (unsigned short)(u >> 16);
}

// ---------------------------------------------------------------------------
// Kernel 1: embedding gather. One block per output row, float4 copy.
__global__ void gather_rows(const int* __restrict__ ids,
                            const float* __restrict__ table,
                            float* __restrict__ out) {
    int row = blockIdx.x;
    int id  = ids[row];
    const f32x4* src = (const f32x4*)(table + (size_t)id * D_SZ);
    f32x4*       dst = (f32x4*)(out + (size_t)row * D_SZ);
    __builtin_nontemporal_store(src[threadIdx.x], &dst[threadIdx.x]);
}

// ---------------------------------------------------------------------------
// Kernel 2: cast embeds f32 -> bf16 (A matrix [M][K]), 8 elems/thread.
__global__ void cast_f32_bf16(const float* __restrict__ in,
                              unsigned short* __restrict__ out, int n8) {
    int i = blockIdx.x * blockDim.x + threadIdx.x;
    int stride = gridDim.x * blockDim.x;
    for (; i < n8; i += stride) {
        const float4* p = (const float4*)(in + (size_t)i * 8);
        float4 a = p[0], b = p[1];
        union { unsigned short s[8]; uint4 v; } r;
        r.s[0] = f32_to_bf16_rne(a.x); r.s[1] = f32_to_bf16_rne(a.y);
        r.s[2] = f32_to_bf16_rne(a.z); r.s[3] = f32_to_bf16_rne(a.w);
        r.s[4] = f32_to_bf16_rne(b.x); r.s[5] = f32_to_bf16_rne(b.y);
        r.s[6] = f32_to_bf16_rne(b.z); r.s[7] = f32_to_bf16_rne(b.w);
        ((uint4*)out)[i] = r.v;
    }
}

// ---------------------------------------------------------------------------
// Kernel 3: transpose+cast out_weight [K=1024][V=32000] f32 -> Bt [V][K] bf16.
__global__ void transpose_cast(const float* __restrict__ w,
                               unsigned short* __restrict__ bt) {
    __shared__ unsigned short tile[32][34];
    int n0 = blockIdx.x * 32;          // column block in V
    int k0 = blockIdx.y * 32;          // row block in K
    int r = threadIdx.x >> 5;          // 0..7
    int c = threadIdx.x & 31;          // 0..31
#pragma unroll
    for (int rr = 0; rr < 32; rr += 8) {
        float v = w[(size_t)(k0 + r + rr) * V_SZ + (n0 + c)];
        tile[c][r + rr] = f32_to_bf16_rne(v);
    }
    __syncthreads();
    int nl = threadIdx.x >> 3;         // 0..31
    int ks = threadIdx.x & 7;          // 0..7  (4 bf16 = 8B per thread)
    union { unsigned short s[4]; uint2 v; } r2;
#pragma unroll
    for (int j = 0; j < 4; ++j) r2.s[j] = tile[nl][ks * 4 + j];
    ((uint2*)(bt + (size_t)(n0 + nl) * D_SZ + k0))[ks] = r2.v;
}

// ---------------------------------------------------------------------------
// Kernel 4: PERSISTENT producer/consumer bf16 GEMM.
// 384 threads: waves 0-3 compute (64x128 output each, 1/SIMD), waves 4-5
// stage via global_load_lds. Tile 128x256, BK=64, TRIPLE-buffered 48 KB
// slabs (144 KB LDS). Producers own all staging + counted vmcnt; compute
// waves' vmcnt FIFO holds only C-stores and is NEVER waited on -> the
// per-tile 128-store burst overlaps the next tile's compute. One raw
// s_barrier per step. k-split LDS layout (0 bank conflicts measured).
// Fixed bm per block (XCD-pinned A slice in L2); bn = q0 + 4r sweep.
// BUGFIX r11: tail race -- at g = G-2 no new batch is staged, so only 24
// loads are outstanding and vmcnt(24) was a NO-OP: the barrier released
// consumers into the final K-step before batch G-1 landed (replay-timing
// dependent corruption of each block's last bn tile). Tail now waits
// vmcnt(0) when g+2 >= G.
#define BM 128
#define BN 256
#define BK 64
#define BUF_SZ 49152        // 48 KB: A[8][128][16B] (16K) + B[8][256][16B] (32K)

static __device__ __forceinline__ void gload_lds16(const unsigned short* g, void* lds) {
    __builtin_amdgcn_global_load_lds(
        (const __attribute__((address_space(1))) void*)g,
        (__attribute__((address_space(3))) void*)lds,
        16, 0, 0);
}

__global__ __launch_bounds__(384)
void gemm_ws(const unsigned short* __restrict__ A,
             const unsigned short* __restrict__ Bt,
             float* __restrict__ C) {
    __shared__ __align__(16) char lds[3 * BUF_SZ];   // 144 KB

    const int tid  = threadIdx.x;
    const int lane = tid & 63;
    const int w    = tid >> 6;           // 0..5

    const int bid = blockIdx.x;
    const int xcd = bid & 7;
    const int jj  = bid >> 3;            // 0..31
    const int bmi = xcd * 8 + (jj & 7);  // 0..63 (8 bm per XCD = 2 MB A slice)
    const int q0  = jj >> 3;             // 0..3
    const int nt  = (q0 == 0) ? 32 : 31; // bn tiles: q0 + 4r <= 124
    const int G   = nt * 16;             // total K-steps
    const int bm0 = bmi * BM;

    if (w >= 4) {
        // ------------------------- producer waves -------------------------
        const int pw = w - 4;            // 0 or 1
        const int lane16 = lane * 16;
        const unsigned short* pA = A + (size_t)(bm0 + lane) * D_SZ;
        const unsigned short* pB = Bt + ((size_t)(q0 * BN) + lane) * D_SZ;
        const size_t bnstride = (size_t)4 * BN * D_SZ;

        int t2 = 0;                      // K-step within tile being staged

        // stage one 48 KB batch (this wave's 24 slots) into buffer cc
        auto STAGE = [&](int cc) {
            char* bp = (char*)lds + cc * BUF_SZ;
            const int koff = t2 * 64;
            if (pw == 0) {
#pragma unroll
                for (int s = 0; s < 16; ++s) {       // A: hi 0-7, rowgroups 0-1
                    const int rg = s & 1, hi = s >> 1;
                    gload_lds16(pA + (size_t)rg * 64 * D_SZ + koff + hi * 8,
                                bp + hi * 2048 + rg * 1024 + lane16);
                }
#pragma unroll
                for (int u = 0; u < 8; ++u) {        // B: hi 0-1, rowgroups 0-3
                    const int hi = u >> 2, rg = u & 3;
                    gload_lds16(pB + (size_t)rg * 64 * D_SZ + koff + hi * 8,
                                bp + 16384 + hi * 4096 + rg * 1024 + lane16);
                }
            } else {
#pragma unroll
                for (int u = 8; u < 32; ++u) {       // B: hi 2-7, rowgroups 0-3
                    const int hi = u >> 2, rg = u & 3;
                    gload_lds16(pB + (size_t)rg * 64 * D_SZ + koff + hi * 8,
                                bp + 16384 + hi * 4096 + rg * 1024 + lane16);
                }
            }
        };
        auto ADV = [&]() { if (++t2 == 16) { t2 = 0; pB += bnstride; } };

        // Prologue: batches 0,1 -> buf0,buf1; ensure batch 0 landed.
        STAGE(0); ADV();
        STAGE(1); ADV();
        asm volatile("s_waitcnt vmcnt(24)" ::: "memory");
        __builtin_amdgcn_s_barrier();

        int c2 = 2;                      // buffer for batch g+2
        for (int g = 0; g < G; ++g) {
            if (g + 2 < G) {
                STAGE(c2); ADV();
                // batches g+1, g+2 outstanding (48); retire to 24 -> g+1 landed
                asm volatile("s_waitcnt vmcnt(24)" ::: "memory");
            } else {
                // tail: nothing new staged; drain everything so the last
                // batch (G-1) is guaranteed in LDS before the barrier.
                asm volatile("s_waitcnt vmcnt(0)" ::: "memory");
            }
            __builtin_amdgcn_sched_barrier(0);
            __builtin_amdgcn_s_barrier();
            if (++c2 == 3) c2 = 0;
        }
    } else {
        // ------------------------- compute waves --------------------------
        const int wm = w & 1;            // M half (64 rows)
        const int wn = w >> 1;           // N half (128 cols)
        const int hi2 = lane >> 5, l31 = lane & 31;
        const int arow16 = (wm * 64 + l31) * 16;    // + mg*512
        const int brow16 = (wn * 128 + l31) * 16;   // + ng*512

        f32x16 acc[2][4];                // [mg][ng]
#pragma unroll
        for (int mg = 0; mg < 2; ++mg)
#pragma unroll
            for (int ng = 0; ng < 4; ++ng)
#pragma unroll
                for (int e = 0; e < 16; ++e) acc[mg][ng][e] = 0.0f;

        __builtin_amdgcn_s_barrier();    // match producer prologue barrier

        int c = 0;
        for (int g = 0; g < G; ++g) {
            const char* Ab = (const char*)lds + c * BUF_SZ;
            const char* Bb = Ab + 16384;

            bf16x8 a[2][4];              // [mg][kk]
#pragma unroll
            for (int mg = 0; mg < 2; ++mg)
#pragma unroll
                for (int kk = 0; kk < 4; ++kk)
                    a[mg][kk] = *(const bf16x8*)(Ab + kk * 4096 + hi2 * 2048
                                                 + arow16 + mg * 512);
            __builtin_amdgcn_s_setprio(1);
#pragma unroll
            for (int ng = 0; ng < 4; ++ng) {
                bf16x8 b0 = *(const bf16x8*)(Bb +  0       + hi2 * 4096 + brow16 + ng * 512);
                bf16x8 b1 = *(const bf16x8*)(Bb +  8192    + hi2 * 4096 + brow16 + ng * 512);
                bf16x8 b2 = *(const bf16x8*)(Bb + 16384    + hi2 * 4096 + brow16 + ng * 512);
                bf16x8 b3 = *(const bf16x8*)(Bb + 24576    + hi2 * 4096 + brow16 + ng * 512);
#pragma unroll
                for (int mg = 0; mg < 2; ++mg) {
                    acc[mg][ng] = __builtin_amdgcn_mfma_f32_32x32x16_bf16(a[mg][0], b0, acc[mg][ng], 0, 0, 0);
                    acc[mg][ng] = __builtin_amdgcn_mfma_f32_32x32x16_bf16(a[mg][1], b1, acc[mg][ng], 0, 0, 0);
                    acc[mg][ng] = __builtin_amdgcn_mfma_f32_32x32x16_bf16(a[mg][2], b2, acc[mg][ng], 0, 0, 0);
                    acc[mg][ng] = __builtin_amdgcn_mfma_f32_32x32x16_bf16(a[mg][3], b3, acc[mg][ng], 0, 0, 0);
                }
            }
            __builtin_amdgcn_s_setprio(0);
            __builtin_amdgcn_sched_barrier(0);
            __builtin_amdgcn_s_barrier();
            if (++c == 3) c = 0;

            if ((g & 15) == 15) {
                // Tile epilogue: 128 nt stores (never vmcnt-waited; they
                // retire in background under the next tile's compute).
                const int r = g >> 4;
                const int bn0e = (q0 + 4 * r) * BN;
#pragma unroll
                for (int mg = 0; mg < 2; ++mg)
#pragma unroll
                    for (int ng = 0; ng < 4; ++ng) {
                        float* basep = C + (size_t)(bm0 + wm * 64 + mg * 32 + hi2 * 4) * V_SZ
                                       + bn0e + wn * 128 + ng * 32 + l31;
#pragma unroll
                        for (int e = 0; e < 16; ++e) {
                            const int roff = (e & 3) + 8 * (e >> 2);
                            __builtin_nontemporal_store(acc[mg][ng][e],
                                                        basep + (size_t)roff * V_SZ);
                        }
#pragma unroll
                        for (int e = 0; e < 16; ++e) acc[mg][ng][e] = 0.0f;
                    }
            }
        }
    }
}

// ---------------------------------------------------------------------------
extern "C" void kernel_launch(void* const* d_in, const int* in_sizes, int n_in,
                              void* d_out, int out_size, void* d_ws, size_t ws_size,
                              hipStream_t stream) {
    const int*   ids        = (const int*)d_in[0];       // [B,S] = 8192
    const float* embeds     = (const float*)d_in[1];     // [B,S,D]
    const float* in_weight  = (const float*)d_in[2];     // [V,D]
    const float* out_weight = (const float*)d_in[3];     // [D,V]

    float* out_embedded = (float*)d_out;                       // M*D floats
    float* out_logits   = (float*)d_out + (size_t)M_SZ * D_SZ; // M*V floats

    // workspace: A bf16 [M][K] (16 MB) + Bt bf16 [V][K] (64 MB) = ~82 MB
    unsigned short* Abf  = (unsigned short*)d_ws;
    unsigned short* Btbf = Abf + (size_t)M_SZ * D_SZ;

    gather_rows<<<M_SZ, 256, 0, stream>>>(ids, in_weight, out_embedded);
    cast_f32_bf16<<<2048, 256, 0, stream>>>(embeds, Abf, M_SZ * D_SZ / 8);
    transpose_cast<<<dim3(V_SZ / 32, D_SZ / 32), 32 * 8, 0, stream>>>(out_weight, Btbf);
    gemm_ws<<<dim3(256), 384, 0, stream>>>(Abf, Btbf, out_logits);
}

// Round 13
// 946.348 us; speedup vs baseline: 1.1080x; 1.1080x over previous
//
#include <hip/hip_runtime.h>
#include <hip/hip_bf16.h>
#include <stdint.h>

// Problem constants (from reference)
#define V_SZ 32000
#define D_SZ 1024          // = K
#define M_SZ 8192          // B*S = 4*2048

typedef __attribute__((ext_vector_type(8))) short bf16x8;
typedef __attribute__((ext_vector_type(4))) float f32x4;
typedef __attribute__((ext_vector_type(16))) float f32x16;

static __device__ __forceinline__ unsigned short f32_to_bf16_rne(float f) {
    union { float f; uint32_t u; } v; v.f = f;
    uint32_t u = v.u;
    uint32_t lsb = (u >> 16) & 1;
    u += 0x7fffu + lsb;
    return (unsigned short)(u >> 16);
}

// ---------------------------------------------------------------------------
// Kernel 1: embedding gather. One block per output row, float4 copy.
__global__ void gather_rows(const int* __restrict__ ids,
                            const float* __restrict__ table,
                            float* __restrict__ out) {
    int row = blockIdx.x;
    int id  = ids[row];
    const f32x4* src = (const f32x4*)(table + (size_t)id * D_SZ);
    f32x4*       dst = (f32x4*)(out + (size_t)row * D_SZ);
    __builtin_nontemporal_store(src[threadIdx.x], &dst[threadIdx.x]);
}

// ---------------------------------------------------------------------------
// Kernel 2: cast embeds f32 -> bf16 (A matrix [M][K]), 8 elems/thread.
__global__ void cast_f32_bf16(const float* __restrict__ in,
                              unsigned short* __restrict__ out, int n8) {
    int i = blockIdx.x * blockDim.x + threadIdx.x;
    int stride = gridDim.x * blockDim.x;
    for (; i < n8; i += stride) {
        const float4* p = (const float4*)(in + (size_t)i * 8);
        float4 a = p[0], b = p[1];
        union { unsigned short s[8]; uint4 v; } r;
        r.s[0] = f32_to_bf16_rne(a.x); r.s[1] = f32_to_bf16_rne(a.y);
        r.s[2] = f32_to_bf16_rne(a.z); r.s[3] = f32_to_bf16_rne(a.w);
        r.s[4] = f32_to_bf16_rne(b.x); r.s[5] = f32_to_bf16_rne(b.y);
        r.s[6] = f32_to_bf16_rne(b.z); r.s[7] = f32_to_bf16_rne(b.w);
        ((uint4*)out)[i] = r.v;
    }
}

// ---------------------------------------------------------------------------
// Kernel 3: transpose+cast out_weight [K=1024][V=32000] f32 -> Bt [V][K] bf16.
__global__ void transpose_cast(const float* __restrict__ w,
                               unsigned short* __restrict__ bt) {
    __shared__ unsigned short tile[32][34];
    int n0 = blockIdx.x * 32;          // column block in V
    int k0 = blockIdx.y * 32;          // row block in K
    int r = threadIdx.x >> 5;          // 0..7
    int c = threadIdx.x & 31;          // 0..31
#pragma unroll
    for (int rr = 0; rr < 32; rr += 8) {
        float v = w[(size_t)(k0 + r + rr) * V_SZ + (n0 + c)];
        tile[c][r + rr] = f32_to_bf16_rne(v);
    }
    __syncthreads();
    int nl = threadIdx.x >> 3;         // 0..31
    int ks = threadIdx.x & 7;          // 0..7  (4 bf16 = 8B per thread)
    union { unsigned short s[4]; uint2 v; } r2;
#pragma unroll
    for (int j = 0; j < 4; ++j) r2.s[j] = tile[nl][ks * 4 + j];
    ((uint2*)(bt + (size_t)(n0 + nl) * D_SZ + k0))[ks] = r2.v;
}

// ---------------------------------------------------------------------------
// Kernel 4: PERSISTENT bf16 GEMM, TWO blocks per CU (two independent barrier
// domains -> when one block is in its read/stage/store phase the other's
// waves feed the matrix pipe; r8-r12 showed a single barrier domain
// serializes LDS+MFMA+VALU ~perfectly).
// Block: 256 thr (4 waves 2Mx2N, wave tile 128x64), tile 256x128, BK=32,
// TRIPLE-buffered 24 KB slabs (72 KB/block; 2x72=144 <= 160 KB/CU).
// k-split LDS layout (0 bank conflicts measured r1-r12). Homogeneous
// staging: 6 gload_lds/thread/step; stage s+2, counted vmcnt(6) retires
// s+1; ONE barrier per step; continuous across bn tiles (no drains).
// XCD map: xcd owns 4 bm (2 MB A slice in L2); bn = q0 + 16r sweep in
// cross-XCD lockstep; bijective over 32x250 tiles (16/15 per block).
#define BM 256
#define BN 128
#define BK 32
#define SLAB 24576          // A [4][256][16B] (16K) + B [4][128][16B] (8K)

static __device__ __forceinline__ void gload_lds16(const unsigned short* g, void* lds) {
    __builtin_amdgcn_global_load_lds(
        (const __attribute__((address_space(1))) void*)g,
        (__attribute__((address_space(3))) void*)lds,
        16, 0, 0);
}

__global__ __launch_bounds__(256, 2)
void gemm_2dom(const unsigned short* __restrict__ A,
               const unsigned short* __restrict__ Bt,
               float* __restrict__ C) {
    __shared__ __align__(16) char lds[3 * SLAB];   // 72 KB

    const int tid  = threadIdx.x;
    const int lane = tid & 63;
    const int w    = tid >> 6;           // 0..3
    const int wm   = w >> 1;             // 0..1 (128-row half)
    const int wn   = w & 1;              // 0..1 (64-col half)

    const int bid = blockIdx.x;          // 512 blocks = 2 per CU
    const int xcd = bid & 7;
    const int b6  = bid >> 3;            // 0..63
    const int bm0 = (xcd * 4 + (b6 & 3)) * BM;   // 32 bm tiles, 4 per XCD
    const int q0  = b6 >> 2;             // 0..15
    const int ntiles = (q0 < 10) ? 16 : 15;      // bn = q0 + 16r <= 249
    const int S   = ntiles * 32;         // global K-steps (BK=32, 32/tile)

    // staging invariants
    const unsigned short* aRow = A + (size_t)(bm0 + tid) * D_SZ;  // + t2*32 + hi*8
    const int  brow = tid & 127;
    const int  hib0 = (tid >> 7) * 2;    // 0 or 2
    const size_t browD = (size_t)brow * D_SZ;

    // stage global step s2 into buffer at byte offset bufo
#define STAGE(s2, bufo) do { \
    const int r2_ = (s2) >> 5, t2_ = (s2) & 31; \
    const int ko_ = t2_ * 32; \
    char* bp_ = (char*)lds + (bufo); \
    const unsigned short* pa_ = aRow + ko_; \
    gload_lds16(pa_,      bp_ +         tid * 16); \
    gload_lds16(pa_ + 8,  bp_ + 4096  + tid * 16); \
    gload_lds16(pa_ + 16, bp_ + 8192  + tid * 16); \
    gload_lds16(pa_ + 24, bp_ + 12288 + tid * 16); \
    const unsigned short* pb_ = Bt + (size_t)(q0 + 16 * r2_) * 128 * D_SZ \
                                + browD + ko_ + hib0 * 8; \
    gload_lds16(pb_,     bp_ + 16384 + hib0 * 2048 + brow * 16); \
    gload_lds16(pb_ + 8, bp_ + 16384 + (hib0 + 1) * 2048 + brow * 16); \
} while (0)

    // Prologue: steps 0,1 -> buf0,buf1; wait step 0 (oldest 6 of 12).
    STAGE(0, 0);
    STAGE(1, SLAB);
    asm volatile("s_waitcnt vmcnt(6)" ::: "memory");
    __builtin_amdgcn_s_barrier();

    f32x16 acc[4][2];
#pragma unroll
    for (int mg = 0; mg < 4; ++mg)
#pragma unroll
        for (int ng = 0; ng < 2; ++ng)
#pragma unroll
            for (int e = 0; e < 16; ++e) acc[mg][ng][e] = 0.0f;

    // 32x32x16 frag: row/col = lane&31, k-group = kk*2 + (lane>>5)
    const int hi2 = lane >> 5, l31 = lane & 31;
    const int aoff = wm * 2048 + l31 * 16;            // + mg*512 + (kk*2+hi2)*4096
    const int boff = 16384 + wn * 1024 + l31 * 16;    // + ng*512 + (kk*2+hi2)*2048

    int bufC = 0;
    int bufS = 2 * SLAB;

    for (int s = 0; s < S; ++s) {
        if (s + 2 < S) STAGE(s + 2, bufS);

        const char* base = (const char*)lds + bufC;
        bf16x8 a[4][2], b[2][2];
#pragma unroll
        for (int mg = 0; mg < 4; ++mg)
#pragma unroll
            for (int kk = 0; kk < 2; ++kk)
                a[mg][kk] = *(const bf16x8*)(base + (kk * 2 + hi2) * 4096
                                             + aoff + mg * 512);
#pragma unroll
        for (int ng = 0; ng < 2; ++ng)
#pragma unroll
            for (int kk = 0; kk < 2; ++kk)
                b[ng][kk] = *(const bf16x8*)(base + (kk * 2 + hi2) * 2048
                                             + boff + ng * 512);

        __builtin_amdgcn_s_setprio(1);
#pragma unroll
        for (int kk = 0; kk < 2; ++kk)
#pragma unroll
            for (int mg = 0; mg < 4; ++mg)
#pragma unroll
                for (int ng = 0; ng < 2; ++ng)
                    acc[mg][ng] = __builtin_amdgcn_mfma_f32_32x32x16_bf16(
                        a[mg][kk], b[ng][kk], acc[mg][ng], 0, 0, 0);
        __builtin_amdgcn_s_setprio(0);

        if (s + 2 < S) { asm volatile("s_waitcnt vmcnt(6)" ::: "memory"); }
        else           { asm volatile("s_waitcnt vmcnt(0)" ::: "memory"); }
        __builtin_amdgcn_s_barrier();

        bufC += SLAB; if (bufC == 3 * SLAB) bufC = 0;
        bufS += SLAB; if (bufS == 3 * SLAB) bufS = 0;

        if ((s & 31) == 31) {
            // Tile epilogue (overlapped by the co-resident block's compute).
            // 32x32 C frag: col = lane&31, row = (e&3)+8*(e>>2)+4*(lane>>5).
            const int r = s >> 5;
            const int ccol0 = (q0 + 16 * r) * BN + wn * 64 + l31;
            const int crow0 = bm0 + wm * 128 + hi2 * 4;
#pragma unroll
            for (int mg = 0; mg < 4; ++mg)
#pragma unroll
                for (int ng = 0; ng < 2; ++ng) {
                    float* basep = C + (size_t)(crow0 + mg * 32) * V_SZ
                                   + ccol0 + ng * 32;
#pragma unroll
                    for (int e = 0; e < 16; ++e) {
                        const int roff = (e & 3) + 8 * (e >> 2);
                        __builtin_nontemporal_store(acc[mg][ng][e],
                                                    basep + (size_t)roff * V_SZ);
                    }
#pragma unroll
                    for (int e = 0; e < 16; ++e) acc[mg][ng][e] = 0.0f;
                }
        }
    }
#undef STAGE
}

// ---------------------------------------------------------------------------
extern "C" void kernel_launch(void* const* d_in, const int* in_sizes, int n_in,
                              void* d_out, int out_size, void* d_ws, size_t ws_size,
                              hipStream_t stream) {
    const int*   ids        = (const int*)d_in[0];       // [B,S] = 8192
    const float* embeds     = (const float*)d_in[1];     // [B,S,D]
    const float* in_weight  = (const float*)d_in[2];     // [V,D]
    const float* out_weight = (const float*)d_in[3];     // [D,V]

    float* out_embedded = (float*)d_out;                       // M*D floats
    float* out_logits   = (float*)d_out + (size_t)M_SZ * D_SZ; // M*V floats

    // workspace: A bf16 [M][K] (16 MB) + Bt bf16 [V][K] (64 MB) = ~82 MB
    unsigned short* Abf  = (unsigned short*)d_ws;
    unsigned short* Btbf = Abf + (size_t)M_SZ * D_SZ;

    gather_rows<<<M_SZ, 256, 0, stream>>>(ids, in_weight, out_embedded);
    cast_f32_bf16<<<2048, 256, 0, stream>>>(embeds, Abf, M_SZ * D_SZ / 8);
    transpose_cast<<<dim3(V_SZ / 32, D_SZ / 32), 256, 0, stream>>>(out_weight, Btbf);
    gemm_2dom<<<dim3(512), 256, 0, stream>>>(Abf, Btbf, out_logits);
}